// Round 1
// baseline (120.646 us; speedup 1.0000x reference)
//
#include <hip/hip_runtime.h>

#define SQd 4096
#define SKVd 4096
#define DDIM 64
#define BK 32                          // keys per tile
#define NG 8                           // key groups (waves) per block
#define NTILES (SKVd / BK)             // 128 tiles per batch
#define NCHUNK (NTILES / 2)            // 64 chunks (64 keys) per batch
#define TPG (NTILES / NG)              // 16 tiles per wave
#define CPG (TPG / 2)                  // 8 chunks per wave
#define KWS_BYTES ((size_t)4 * NTILES * 2048)   // 1 MB fp8 K
#define BROWS 32                       // q-rows per block (= per wave now)

typedef float floatx4  __attribute__((ext_vector_type(4)));
typedef float floatx16 __attribute__((ext_vector_type(16)));
typedef int   intx8    __attribute__((ext_vector_type(8)));

// Word-select must be an immediate constant -> template parameter.
template <bool HI>
__device__ inline int pk2(float a, float b, int old) {
    return __builtin_amdgcn_cvt_pk_fp8_f32(a, b, old, HI);
}

__device__ inline intx8 mk8(int4 a, int4 b) {
    intx8 r;
    r[0] = a.x; r[1] = a.y; r[2] = a.z; r[3] = a.w;
    r[4] = b.x; r[5] = b.y; r[6] = b.z; r[7] = b.w;
    return r;
}

// LDS: cross-group combine only (8 key-groups -> 4 slots, 2 rounds).
// 35840 B per block -> 2 blocks/CU co-resident.
struct CombS {
    float Ored[BROWS][4][68];
    float Lred[BROWS][NG];
};

// ---------------- Pre-pass: pack K and V for 32x32x64 f8f6f4 MFMA ----------
// K A-frag  (per 32-key tile, 2048 B): byte(lane*32 + j) =
//     fp8( K[tile*32 + (lane&31)][(lane>>5)*32 + j] ),  j = 0..31
// V B-frag  (per 64-key chunk, per d-half, 2048 B): byte(lane*32 + pt*16 + r) =
//     fp8( V[chunk*64 + pt*32 + (r&3)+8*(r>>2)+4*(lane>>5)][h*32 + (lane&31)] )
// The key permutation matches the 32x32 MFMA C-layout of QK^T, so exp'd P
// bytes feed the PV A-operand directly.
__global__ __launch_bounds__(256)
void prepack_kernel(const float* __restrict__ k, const float* __restrict__ v,
                    char* __restrict__ ws)
{
    __shared__ __align__(16) float Kt[BK][68];
    __shared__ __align__(16) float Vt[BK][68];

    const int blk  = blockIdx.x;          // b*NTILES + tile
    const int b    = blk >> 7;
    const int tile = blk & (NTILES - 1);
    const int tid  = threadIdx.x;

    const size_t base = ((size_t)b * SKVd + tile * BK) * DDIM;
    {
        const int row = tid >> 3, col = (tid & 7) * 8;
        const float4 k0 = *(const float4*)(k + base + (size_t)row * DDIM + col);
        const float4 k1 = *(const float4*)(k + base + (size_t)row * DDIM + col + 4);
        *(float4*)&Kt[row][col] = k0; *(float4*)&Kt[row][col + 4] = k1;
        const float4 v0 = *(const float4*)(v + base + (size_t)row * DDIM + col);
        const float4 v1 = *(const float4*)(v + base + (size_t)row * DDIM + col + 4);
        *(float4*)&Vt[row][col] = v0; *(float4*)&Vt[row][col + 4] = v1;
    }
    __syncthreads();

    const int lane = tid & 63;
    const int q4   = tid >> 6;            // 0..3: sub-slice of the lane's 32 B
    const int l31  = lane & 31;
    const int u    = lane >> 5;

    // K pack: 8 bytes per thread
    {
        const float* s = &Kt[l31][u * 32 + q4 * 8];
        int w0 = pk2<false>(s[0], s[1], 0); w0 = pk2<true>(s[2], s[3], w0);
        int w1 = pk2<false>(s[4], s[5], 0); w1 = pk2<true>(s[6], s[7], w1);
        int2 o2; o2.x = w0; o2.y = w1;
        *(int2*)(ws + (size_t)(b * NTILES + tile) * 2048 + lane * 32 + q4 * 8) = o2;
    }
    // V pack: 8 bytes per thread (h = d-half, rh = reg offset)
    {
        const int h  = q4 >> 1;
        const int rh = (q4 & 1) * 8;
        float p[8];
        #pragma unroll
        for (int i = 0; i < 8; ++i) {
            const int r   = rh + i;
            const int key = (r & 3) + 8 * (r >> 2) + 4 * u;
            p[i] = Vt[key][h * 32 + l31];
        }
        int w0 = pk2<false>(p[0], p[1], 0); w0 = pk2<true>(p[2], p[3], w0);
        int w1 = pk2<false>(p[4], p[5], 0); w1 = pk2<true>(p[6], p[7], w1);
        int2 o2; o2.x = w0; o2.y = w1;
        const size_t voff = KWS_BYTES
            + ((size_t)(b * NCHUNK + (tile >> 1)) * 2 + h) * 2048
            + lane * 32 + (tile & 1) * 16 + rh;
        *(int2*)(ws + voff) = o2;
    }
}

// ---------------- Main kernel ---------------------------------------------
// Wave = 32 q-rows x 512 keys (8 chunks of 64 keys). Per chunk:
//   2x QK mfma_scale_32x32x64 (one per 32-key tile, K = full D=64)
//   32x exp2 + 16x cvt_pk -> P A-frag (8 dwords)
//   2x PV mfma_scale_32x32x64 (d 0-31 / 32-63)
// vs the previous 16 x 16x16x32 MFMAs per tile: per-wave MFMA count 256 -> 32.
__global__ __launch_bounds__(512, 4)
void fattn_kernel(const float* __restrict__ q, const int* __restrict__ isf_p,
                  const char* __restrict__ kws, const char* __restrict__ vws,
                  float* __restrict__ out)
{
    __shared__ CombS C;

    const int tid  = threadIdx.x;
    const int g    = tid >> 6;    // key group 0..7 (512 keys)
    const int lane = tid & 63;
    const int l31  = lane & 31;
    const int u    = lane >> 5;

    const int bidx  = blockIdx.x;       // 0..511
    const int b     = bidx >> 7;        // batch
    const int qbase = (bidx & 127) * BROWS;

    // exp(s) = 2^(s*log2e); constant -4 folded into the MFMA C-init keeps
    // p' = e^(s-4) within e4m3 range.
    const float scale = 1.44269504088896340736f / (float)(*isf_p);
    const float SINIT = -4.0f * 1.44269504088896340736f;

    // Q B-frag: byte(lane: j) = fp8(Q[qbase + l31][u*32 + j] * scale)
    intx8 qf;
    {
        const float* qp = q + ((size_t)b * SQd + qbase + l31) * DDIM + u * 32;
        #pragma unroll
        for (int d = 0; d < 8; ++d) {
            const float4 a = *(const float4*)(qp + 4 * d);
            int w = pk2<false>(a.x * scale, a.y * scale, 0);
            w     = pk2<true >(a.z * scale, a.w * scale, w);
            qf[d] = w;
        }
    }

    const char* kg = kws + (size_t)(b * NTILES + g * TPG) * 2048 + lane * 32;
    const char* vg = vws + (size_t)(b * NCHUNK + g * CPG) * 4096 + lane * 32;
    const int cph  = bidx & (CPG - 1);   // decorrelate L2 streams across CUs

    floatx16 sinit16, o0, o1;
    #pragma unroll
    for (int i = 0; i < 16; ++i) { sinit16[i] = SINIT; o0[i] = 0.f; o1[i] = 0.f; }
    float l_acc = 0.f;

    int4 kA0, kA1, kB0, kB1, vA0, vA1, vB0, vB1;
    auto loadK = [&](int c) {
        const size_t off = (size_t)((c + cph) & (CPG - 1)) * 4096;
        kA0 = *(const int4*)(kg + off);        kA1 = *(const int4*)(kg + off + 16);
        kB0 = *(const int4*)(kg + off + 2048); kB1 = *(const int4*)(kg + off + 2064);
    };
    auto loadV = [&](int c) {
        const size_t off = (size_t)((c + cph) & (CPG - 1)) * 4096;
        vA0 = *(const int4*)(vg + off);        vA1 = *(const int4*)(vg + off + 16);
        vB0 = *(const int4*)(vg + off + 2048); vB1 = *(const int4*)(vg + off + 2064);
    };

    loadK(0); loadV(0);
    #pragma unroll
    for (int c = 0; c < CPG; ++c) {
        // QK^T for both 32-key tiles of the chunk (independent MFMAs).
        // C layout: s[r] = S[key=(r&3)+8*(r>>2)+4u][qrow=l31] + SINIT
        floatx16 se = __builtin_amdgcn_mfma_scale_f32_32x32x64_f8f6f4(
            mk8(kA0, kA1), qf, sinit16, 0, 0, 0, 0x7F7F7F7F, 0, 0x7F7F7F7F);
        floatx16 so = __builtin_amdgcn_mfma_scale_f32_32x32x64_f8f6f4(
            mk8(kB0, kB1), qf, sinit16, 0, 0, 0, 0x7F7F7F7F, 0, 0x7F7F7F7F);
        if (c + 1 < CPG) loadK(c + 1);

        float pe[16], po[16];
        #pragma unroll
        for (int r = 0; r < 16; ++r) pe[r] = __builtin_amdgcn_exp2f(se[r]);
        #pragma unroll
        for (int r = 0; r < 16; ++r) po[r] = __builtin_amdgcn_exp2f(so[r]);

        l_acc += ((((pe[0] + pe[1]) + (pe[2] + pe[3])) + ((pe[4] + pe[5]) + (pe[6] + pe[7])))
               + (((pe[8] + pe[9]) + (pe[10] + pe[11])) + ((pe[12] + pe[13]) + (pe[14] + pe[15]))));
        l_acc += ((((po[0] + po[1]) + (po[2] + po[3])) + ((po[4] + po[5]) + (po[6] + po[7])))
               + (((po[8] + po[9]) + (po[10] + po[11])) + ((po[12] + po[13]) + (po[14] + po[15]))));

        // PV A-frag: byte j = t*16 + r holds p_t[r] — matches V prepack perm.
        intx8 pa;
        #pragma unroll
        for (int d2 = 0; d2 < 4; ++d2) {
            int w = pk2<false>(pe[4 * d2], pe[4 * d2 + 1], 0);
            pa[d2] = pk2<true>(pe[4 * d2 + 2], pe[4 * d2 + 3], w);
        }
        #pragma unroll
        for (int d2 = 0; d2 < 4; ++d2) {
            int w = pk2<false>(po[4 * d2], po[4 * d2 + 1], 0);
            pa[4 + d2] = pk2<true>(po[4 * d2 + 2], po[4 * d2 + 3], w);
        }

        o0 = __builtin_amdgcn_mfma_scale_f32_32x32x64_f8f6f4(
            pa, mk8(vA0, vA1), o0, 0, 0, 0, 0x7F7F7F7F, 0, 0x7F7F7F7F);
        o1 = __builtin_amdgcn_mfma_scale_f32_32x32x64_f8f6f4(
            pa, mk8(vB0, vB1), o1, 0, 0, 0, 0x7F7F7F7F, 0, 0x7F7F7F7F);
        if (c + 1 < CPG) loadV(c + 1);
    }

    // Row denominators: lanes l and l+32 hold complementary key halves of
    // qrow = l31.
    l_acc += __shfl_xor(l_acc, 32);
    if (u == 0) C.Lred[l31][g] = l_acc;

    // Cross-group combine: groups 0-3 write slots, barrier, groups 4-7 add.
    // O layout: o_h[r] = O[qrow=(r&3)+8*(r>>2)+4u][d = h*32 + l31]
    if (g < 4) {
        #pragma unroll
        for (int r = 0; r < 16; ++r) {
            const int row = (r & 3) + 8 * (r >> 2) + 4 * u;
            C.Ored[row][g][l31]      = o0[r];
            C.Ored[row][g][32 + l31] = o1[r];
        }
    }
    __syncthreads();
    if (g >= 4) {
        #pragma unroll
        for (int r = 0; r < 16; ++r) {
            const int row = (r & 3) + 8 * (r >> 2) + 4 * u;
            C.Ored[row][g - 4][l31]      += o0[r];
            C.Ored[row][g - 4][32 + l31] += o1[r];
        }
    }
    __syncthreads();

    // Epilogue: out = attn@v + q; 3x { x += 2q; sigmoid; clamp }. Each thread
    // owns 4 consecutive d of one row (512 thr x 4 = 32 rows x 64 d).
    {
        const int row = tid >> 4;
        const int d4  = (tid & 15) * 4;
        float l = 0.0f;
        #pragma unroll
        for (int gg = 0; gg < NG; ++gg) l += C.Lred[row][gg];
        const float rl = 1.0f / l;
        float xs[4] = {0.f, 0.f, 0.f, 0.f};
        #pragma unroll
        for (int s = 0; s < 4; ++s) {
            const float4 t4 = *(const float4*)&C.Ored[row][s][d4];
            xs[0] += t4.x; xs[1] += t4.y; xs[2] += t4.z; xs[3] += t4.w;
        }
        const size_t idx = ((size_t)b * SQd + qbase + row) * DDIM + d4;
        const float4 q4v = *(const float4*)(q + idx);
        const float qs[4] = {q4v.x, q4v.y, q4v.z, q4v.w};
        #pragma unroll
        for (int c = 0; c < 4; ++c) {
            float x = xs[c] * rl + qs[c];
            #pragma unroll
            for (int itc = 0; itc < 3; ++itc) {
                x = x + 2.0f * qs[c];
                x = 1.0f / (1.0f + __expf(-x));
                x = fminf(fmaxf(x, 0.0f), 1.0f);
            }
            xs[c] = x;
        }
        const float4 r4 = {xs[0], xs[1], xs[2], xs[3]};
        *(float4*)(out + idx) = r4;
    }
}

extern "C" void kernel_launch(void* const* d_in, const int* in_sizes, int n_in,
                              void* d_out, int out_size, void* d_ws, size_t ws_size,
                              hipStream_t stream) {
    const float* q = (const float*)d_in[0];
    const float* k = (const float*)d_in[1];
    const float* v = (const float*)d_in[2];
    const int* isf = (const int*)d_in[3];
    float* out = (float*)d_out;
    char* ws = (char*)d_ws;   // Kws: 1 MB, Vws: 1 MB (fp8)

    prepack_kernel<<<dim3(4 * NTILES), dim3(256), 0, stream>>>(k, v, ws);

    const int nblocks = 4 * (SQd / BROWS);  // 512 blocks x 512 threads, 2/CU
    fattn_kernel<<<dim3(nblocks), dim3(512), 0, stream>>>(
        q, isf, ws, ws + KWS_BYTES, out);
}

// Round 2
// 89.415 us; speedup vs baseline: 1.3493x; 1.3493x over previous
//
#include <hip/hip_runtime.h>

#define SQd 4096
#define SKVd 4096
#define DDIM 64
#define BK 32                          // keys per tile
#define NG 8                           // key groups (waves) per block
#define NTILES (SKVd / BK)             // 128 tiles per batch
#define NCHUNK (NTILES / 2)            // 64 chunks (64 keys) per batch
#define TPG (NTILES / NG)              // 16 tiles per wave
#define CPG (TPG / 2)                  // 8 chunks per wave
#define KWS_BYTES ((size_t)4 * NTILES * 2048)   // 1 MB fp8 K
#define BROWS 32                       // q-rows per block (= per wave now)

typedef float floatx4  __attribute__((ext_vector_type(4)));
typedef float floatx16 __attribute__((ext_vector_type(16)));
typedef int   intx8    __attribute__((ext_vector_type(8)));

// Word-select must be an immediate constant -> template parameter.
template <bool HI>
__device__ inline int pk2(float a, float b, int old) {
    return __builtin_amdgcn_cvt_pk_fp8_f32(a, b, old, HI);
}

__device__ inline intx8 mk8(int4 a, int4 b) {
    intx8 r;
    r[0] = a.x; r[1] = a.y; r[2] = a.z; r[3] = a.w;
    r[4] = b.x; r[5] = b.y; r[6] = b.z; r[7] = b.w;
    return r;
}

// LDS: cross-group combine only (8 key-groups -> 4 slots, 2 rounds).
// 35840 B per block -> 2 blocks/CU co-resident.
struct CombS {
    float Ored[BROWS][4][68];
    float Lred[BROWS][NG];
};

// ---------------- Pre-pass: pack K and V for 32x32x64 f8f6f4 MFMA ----------
// K A-frag  (per 32-key tile, 2048 B): byte(lane*32 + j) =
//     fp8( K[tile*32 + (lane&31)][(lane>>5)*32 + j] ),  j = 0..31
// V B-frag  (per 64-key chunk, per d-half, 2048 B): byte(lane*32 + pt*16 + r) =
//     fp8( V[chunk*64 + pt*32 + (r&3)+8*(r>>2)+4*(lane>>5)][h*32 + (lane&31)] )
// The key permutation matches the 32x32 MFMA C-layout of QK^T, so exp'd P
// bytes feed the PV A-operand directly.
__global__ __launch_bounds__(256)
void prepack_kernel(const float* __restrict__ k, const float* __restrict__ v,
                    char* __restrict__ ws)
{
    __shared__ __align__(16) float Kt[BK][68];
    __shared__ __align__(16) float Vt[BK][68];

    const int blk  = blockIdx.x;          // b*NTILES + tile
    const int b    = blk >> 7;
    const int tile = blk & (NTILES - 1);
    const int tid  = threadIdx.x;

    const size_t base = ((size_t)b * SKVd + tile * BK) * DDIM;
    {
        const int row = tid >> 3, col = (tid & 7) * 8;
        const float4 k0 = *(const float4*)(k + base + (size_t)row * DDIM + col);
        const float4 k1 = *(const float4*)(k + base + (size_t)row * DDIM + col + 4);
        *(float4*)&Kt[row][col] = k0; *(float4*)&Kt[row][col + 4] = k1;
        const float4 v0 = *(const float4*)(v + base + (size_t)row * DDIM + col);
        const float4 v1 = *(const float4*)(v + base + (size_t)row * DDIM + col + 4);
        *(float4*)&Vt[row][col] = v0; *(float4*)&Vt[row][col + 4] = v1;
    }
    __syncthreads();

    const int lane = tid & 63;
    const int q4   = tid >> 6;            // 0..3: sub-slice of the lane's 32 B
    const int l31  = lane & 31;
    const int u    = lane >> 5;

    // K pack: 8 bytes per thread
    {
        const float* s = &Kt[l31][u * 32 + q4 * 8];
        int w0 = pk2<false>(s[0], s[1], 0); w0 = pk2<true>(s[2], s[3], w0);
        int w1 = pk2<false>(s[4], s[5], 0); w1 = pk2<true>(s[6], s[7], w1);
        int2 o2; o2.x = w0; o2.y = w1;
        *(int2*)(ws + (size_t)(b * NTILES + tile) * 2048 + lane * 32 + q4 * 8) = o2;
    }
    // V pack: 8 bytes per thread (h = d-half, rh = reg offset)
    {
        const int h  = q4 >> 1;
        const int rh = (q4 & 1) * 8;
        float p[8];
        #pragma unroll
        for (int i = 0; i < 8; ++i) {
            const int r   = rh + i;
            const int key = (r & 3) + 8 * (r >> 2) + 4 * u;
            p[i] = Vt[key][h * 32 + l31];
        }
        int w0 = pk2<false>(p[0], p[1], 0); w0 = pk2<true>(p[2], p[3], w0);
        int w1 = pk2<false>(p[4], p[5], 0); w1 = pk2<true>(p[6], p[7], w1);
        int2 o2; o2.x = w0; o2.y = w1;
        const size_t voff = KWS_BYTES
            + ((size_t)(b * NCHUNK + (tile >> 1)) * 2 + h) * 2048
            + lane * 32 + (tile & 1) * 16 + rh;
        *(int2*)(ws + voff) = o2;
    }
}

// ---------------- Main kernel ---------------------------------------------
// Wave = 32 q-rows x 512 keys (8 chunks of 64 keys). Per chunk:
//   load 64 B (K both tiles + V both d-halves)
//   tile A: 1x QK mfma_scale_32x32x64 -> exp2 in place -> pack pa[0..3]
//   tile B: 1x QK -> exp2 -> pack pa[4..7]
//   2x PV mfma_scale_32x32x64 (d 0-31 / 32-63)
// Sequential tile processing + no unroll keeps peak live regs ~110 (R1's
// chunk-parallel version spilled: 74 MB scratch writes, VGPR collapsed to 64).
__global__ __launch_bounds__(512, 4)
void fattn_kernel(const float* __restrict__ q, const int* __restrict__ isf_p,
                  const char* __restrict__ kws, const char* __restrict__ vws,
                  float* __restrict__ out)
{
    __shared__ CombS C;

    const int tid  = threadIdx.x;
    const int g    = tid >> 6;    // key group 0..7 (512 keys)
    const int lane = tid & 63;
    const int l31  = lane & 31;
    const int u    = lane >> 5;

    const int bidx  = blockIdx.x;       // 0..511
    const int b     = bidx >> 7;        // batch
    const int qbase = (bidx & 127) * BROWS;

    // exp(s) = 2^(s*log2e); constant -4 folded into the MFMA C-init keeps
    // p' = e^(s-4) within e4m3 range.
    const float scale = 1.44269504088896340736f / (float)(*isf_p);
    const float SINIT = -4.0f * 1.44269504088896340736f;

    // Q B-frag: byte(lane: j) = fp8(Q[qbase + l31][u*32 + j] * scale)
    intx8 qf;
    {
        const float* qp = q + ((size_t)b * SQd + qbase + l31) * DDIM + u * 32;
        #pragma unroll
        for (int d = 0; d < 8; ++d) {
            const float4 a = *(const float4*)(qp + 4 * d);
            int w = pk2<false>(a.x * scale, a.y * scale, 0);
            w     = pk2<true >(a.z * scale, a.w * scale, w);
            qf[d] = w;
        }
    }

    const char* kg = kws + (size_t)(b * NTILES + g * TPG) * 2048 + lane * 32;
    const char* vg = vws + (size_t)(b * NCHUNK + g * CPG) * 4096 + lane * 32;
    const int cph  = bidx & (CPG - 1);   // decorrelate L2 streams across CUs

    floatx16 sinit16, o0, o1;
    #pragma unroll
    for (int i = 0; i < 16; ++i) { sinit16[i] = SINIT; o0[i] = 0.f; o1[i] = 0.f; }
    float l_acc = 0.f;

    #pragma unroll 1
    for (int c = 0; c < CPG; ++c) {
        const size_t off = (size_t)((c + cph) & (CPG - 1)) * 4096;
        // All loads for this chunk issue up front; V latency hides under QK.
        const int4 ka0 = *(const int4*)(kg + off);
        const int4 ka1 = *(const int4*)(kg + off + 16);
        const int4 kb0 = *(const int4*)(kg + off + 2048);
        const int4 kb1 = *(const int4*)(kg + off + 2064);
        const int4 va0 = *(const int4*)(vg + off);
        const int4 va1 = *(const int4*)(vg + off + 16);
        const int4 vb0 = *(const int4*)(vg + off + 2048);
        const int4 vb1 = *(const int4*)(vg + off + 2064);

        intx8 pa;
        // ---- tile A: s -> exp (in place) -> pack pa[0..3] -> release ----
        {
            floatx16 s = __builtin_amdgcn_mfma_scale_f32_32x32x64_f8f6f4(
                mk8(ka0, ka1), qf, sinit16, 0, 0, 0, 0x7F7F7F7F, 0, 0x7F7F7F7F);
            #pragma unroll
            for (int r = 0; r < 16; ++r) s[r] = __builtin_amdgcn_exp2f(s[r]);
            l_acc += ((((s[0] + s[1]) + (s[2] + s[3])) + ((s[4] + s[5]) + (s[6] + s[7])))
                   + (((s[8] + s[9]) + (s[10] + s[11])) + ((s[12] + s[13]) + (s[14] + s[15]))));
            #pragma unroll
            for (int d2 = 0; d2 < 4; ++d2) {
                int w = pk2<false>(s[4 * d2], s[4 * d2 + 1], 0);
                pa[d2] = pk2<true>(s[4 * d2 + 2], s[4 * d2 + 3], w);
            }
        }
        // ---- tile B ----
        {
            floatx16 s = __builtin_amdgcn_mfma_scale_f32_32x32x64_f8f6f4(
                mk8(kb0, kb1), qf, sinit16, 0, 0, 0, 0x7F7F7F7F, 0, 0x7F7F7F7F);
            #pragma unroll
            for (int r = 0; r < 16; ++r) s[r] = __builtin_amdgcn_exp2f(s[r]);
            l_acc += ((((s[0] + s[1]) + (s[2] + s[3])) + ((s[4] + s[5]) + (s[6] + s[7])))
                   + (((s[8] + s[9]) + (s[10] + s[11])) + ((s[12] + s[13]) + (s[14] + s[15]))));
            #pragma unroll
            for (int d2 = 0; d2 < 4; ++d2) {
                int w = pk2<false>(s[4 * d2], s[4 * d2 + 1], 0);
                pa[4 + d2] = pk2<true>(s[4 * d2 + 2], s[4 * d2 + 3], w);
            }
        }
        // ---- PV ----
        o0 = __builtin_amdgcn_mfma_scale_f32_32x32x64_f8f6f4(
            pa, mk8(va0, va1), o0, 0, 0, 0, 0x7F7F7F7F, 0, 0x7F7F7F7F);
        o1 = __builtin_amdgcn_mfma_scale_f32_32x32x64_f8f6f4(
            pa, mk8(vb0, vb1), o1, 0, 0, 0, 0x7F7F7F7F, 0, 0x7F7F7F7F);
    }

    // Row denominators: lanes l and l+32 hold complementary key halves of
    // qrow = l31.
    l_acc += __shfl_xor(l_acc, 32);
    if (u == 0) C.Lred[l31][g] = l_acc;

    // Cross-group combine: groups 0-3 write slots, barrier, groups 4-7 add.
    // O layout: o_h[r] = O[qrow=(r&3)+8*(r>>2)+4u][d = h*32 + l31]
    if (g < 4) {
        #pragma unroll
        for (int r = 0; r < 16; ++r) {
            const int row = (r & 3) + 8 * (r >> 2) + 4 * u;
            C.Ored[row][g][l31]      = o0[r];
            C.Ored[row][g][32 + l31] = o1[r];
        }
    }
    __syncthreads();
    if (g >= 4) {
        #pragma unroll
        for (int r = 0; r < 16; ++r) {
            const int row = (r & 3) + 8 * (r >> 2) + 4 * u;
            C.Ored[row][g - 4][l31]      += o0[r];
            C.Ored[row][g - 4][32 + l31] += o1[r];
        }
    }
    __syncthreads();

    // Epilogue: out = attn@v + q; 3x { x += 2q; sigmoid; clamp }. Each thread
    // owns 4 consecutive d of one row (512 thr x 4 = 32 rows x 64 d).
    {
        const int row = tid >> 4;
        const int d4  = (tid & 15) * 4;
        float l = 0.0f;
        #pragma unroll
        for (int gg = 0; gg < NG; ++gg) l += C.Lred[row][gg];
        const float rl = 1.0f / l;
        float xs[4] = {0.f, 0.f, 0.f, 0.f};
        #pragma unroll
        for (int s = 0; s < 4; ++s) {
            const float4 t4 = *(const float4*)&C.Ored[row][s][d4];
            xs[0] += t4.x; xs[1] += t4.y; xs[2] += t4.z; xs[3] += t4.w;
        }
        const size_t idx = ((size_t)b * SQd + qbase + row) * DDIM + d4;
        const float4 q4v = *(const float4*)(q + idx);
        const float qs[4] = {q4v.x, q4v.y, q4v.z, q4v.w};
        #pragma unroll
        for (int c = 0; c < 4; ++c) {
            float x = xs[c] * rl + qs[c];
            #pragma unroll
            for (int itc = 0; itc < 3; ++itc) {
                x = x + 2.0f * qs[c];
                x = 1.0f / (1.0f + __expf(-x));
                x = fminf(fmaxf(x, 0.0f), 1.0f);
            }
            xs[c] = x;
        }
        const float4 r4 = {xs[0], xs[1], xs[2], xs[3]};
        *(float4*)(out + idx) = r4;
    }
}

extern "C" void kernel_launch(void* const* d_in, const int* in_sizes, int n_in,
                              void* d_out, int out_size, void* d_ws, size_t ws_size,
                              hipStream_t stream) {
    const float* q = (const float*)d_in[0];
    const float* k = (const float*)d_in[1];
    const float* v = (const float*)d_in[2];
    const int* isf = (const int*)d_in[3];
    float* out = (float*)d_out;
    char* ws = (char*)d_ws;   // Kws: 1 MB, Vws: 1 MB (fp8)

    prepack_kernel<<<dim3(4 * NTILES), dim3(256), 0, stream>>>(k, v, ws);

    const int nblocks = 4 * (SQd / BROWS);  // 512 blocks x 512 threads, 2/CU
    fattn_kernel<<<dim3(nblocks), dim3(512), 0, stream>>>(
        q, isf, ws, ws + KWS_BYTES, out);
}

// Round 3
// 89.412 us; speedup vs baseline: 1.3493x; 1.0000x over previous
//
#include <hip/hip_runtime.h>

#define SQd 4096
#define SKVd 4096
#define DDIM 64
#define BK 32                          // keys per tile
#define NG 8                           // key groups (waves) per block
#define NTILES (SKVd / BK)             // 128 tiles per batch
#define NCHUNK (NTILES / 2)            // 64 chunks (64 keys) per batch
#define TPG (NTILES / NG)              // 16 tiles per wave
#define CPG (TPG / 2)                  // 8 chunks per wave
#define KWS_BYTES ((size_t)4 * NTILES * 2048)   // 1 MB fp8 K
#define BROWS 32                       // q-rows per block (= per wave now)

typedef float floatx4  __attribute__((ext_vector_type(4)));
typedef float floatx16 __attribute__((ext_vector_type(16)));
typedef int   intx8    __attribute__((ext_vector_type(8)));

// Word-select must be an immediate constant -> template parameter.
template <bool HI>
__device__ inline int pk2(float a, float b, int old) {
    return __builtin_amdgcn_cvt_pk_fp8_f32(a, b, old, HI);
}

__device__ inline intx8 mk8(int4 a, int4 b) {
    intx8 r;
    r[0] = a.x; r[1] = a.y; r[2] = a.z; r[3] = a.w;
    r[4] = b.x; r[5] = b.y; r[6] = b.z; r[7] = b.w;
    return r;
}

// LDS: cross-group combine only (8 key-groups -> 4 slots, 2 rounds).
// 35840 B per block -> 2 blocks/CU co-resident.
struct CombS {
    float Ored[BROWS][4][68];
    float Lred[BROWS][NG];
};

// ---------------- Pre-pass: pack K and V for 32x32x64 f8f6f4 MFMA ----------
// K A-frag  (per 32-key tile, 2048 B): byte(lane*32 + j) =
//     fp8( K[tile*32 + (lane&31)][(lane>>5)*32 + j] ),  j = 0..31
// V B-frag  (per 64-key chunk, per d-half, 2048 B): byte(lane*32 + pt*16 + r) =
//     fp8( V[chunk*64 + pt*32 + (r&3)+8*(r>>2)+4*(lane>>5)][h*32 + (lane&31)] )
// The key permutation matches the 32x32 MFMA C-layout of QK^T, so exp'd P
// bytes feed the PV A-operand directly.
__global__ __launch_bounds__(256)
void prepack_kernel(const float* __restrict__ k, const float* __restrict__ v,
                    char* __restrict__ ws)
{
    __shared__ __align__(16) float Kt[BK][68];
    __shared__ __align__(16) float Vt[BK][68];

    const int blk  = blockIdx.x;          // b*NTILES + tile
    const int b    = blk >> 7;
    const int tile = blk & (NTILES - 1);
    const int tid  = threadIdx.x;

    const size_t base = ((size_t)b * SKVd + tile * BK) * DDIM;
    {
        const int row = tid >> 3, col = (tid & 7) * 8;
        const float4 k0 = *(const float4*)(k + base + (size_t)row * DDIM + col);
        const float4 k1 = *(const float4*)(k + base + (size_t)row * DDIM + col + 4);
        *(float4*)&Kt[row][col] = k0; *(float4*)&Kt[row][col + 4] = k1;
        const float4 v0 = *(const float4*)(v + base + (size_t)row * DDIM + col);
        const float4 v1 = *(const float4*)(v + base + (size_t)row * DDIM + col + 4);
        *(float4*)&Vt[row][col] = v0; *(float4*)&Vt[row][col + 4] = v1;
    }
    __syncthreads();

    const int lane = tid & 63;
    const int q4   = tid >> 6;            // 0..3: sub-slice of the lane's 32 B
    const int l31  = lane & 31;
    const int u    = lane >> 5;

    // K pack: 8 bytes per thread
    {
        const float* s = &Kt[l31][u * 32 + q4 * 8];
        int w0 = pk2<false>(s[0], s[1], 0); w0 = pk2<true>(s[2], s[3], w0);
        int w1 = pk2<false>(s[4], s[5], 0); w1 = pk2<true>(s[6], s[7], w1);
        int2 o2; o2.x = w0; o2.y = w1;
        *(int2*)(ws + (size_t)(b * NTILES + tile) * 2048 + lane * 32 + q4 * 8) = o2;
    }
    // V pack: 8 bytes per thread (h = d-half, rh = reg offset)
    {
        const int h  = q4 >> 1;
        const int rh = (q4 & 1) * 8;
        float p[8];
        #pragma unroll
        for (int i = 0; i < 8; ++i) {
            const int r   = rh + i;
            const int key = (r & 3) + 8 * (r >> 2) + 4 * u;
            p[i] = Vt[key][h * 32 + l31];
        }
        int w0 = pk2<false>(p[0], p[1], 0); w0 = pk2<true>(p[2], p[3], w0);
        int w1 = pk2<false>(p[4], p[5], 0); w1 = pk2<true>(p[6], p[7], w1);
        int2 o2; o2.x = w0; o2.y = w1;
        const size_t voff = KWS_BYTES
            + ((size_t)(b * NCHUNK + (tile >> 1)) * 2 + h) * 2048
            + lane * 32 + (tile & 1) * 16 + rh;
        *(int2*)(ws + voff) = o2;
    }
}

// ---------------- Main kernel ---------------------------------------------
// Wave = 32 q-rows x 512 keys (8 chunks of 64 keys). Per chunk:
//   load K (2 tiles, 16 regs)
//   tile A: QK mfma_scale_32x32x64  -> (V loads issue here, reusing dead K
//           regs) -> exp2 in place -> pack pa[0..3]
//   tile B: QK -> exp2 -> pack pa[4..7]
//   2x PV mfma_scale_32x32x64 (d 0-31 / 32-63)
// Load staggering keeps peak live VGPRs ~114 < the 128 cap of (512,4).
// R1 (all-parallel) spilled 74 MB scratch; R2 (all loads up front) was ~131
// live -> marginal spill inside the hot loop.
__global__ __launch_bounds__(512, 4)
void fattn_kernel(const float* __restrict__ q, const int* __restrict__ isf_p,
                  const char* __restrict__ kws, const char* __restrict__ vws,
                  float* __restrict__ out)
{
    __shared__ CombS C;

    const int tid  = threadIdx.x;
    const int g    = tid >> 6;    // key group 0..7 (512 keys)
    const int lane = tid & 63;
    const int l31  = lane & 31;
    const int u    = lane >> 5;

    const int bidx  = blockIdx.x;       // 0..511
    const int b     = bidx >> 7;        // batch
    const int qbase = (bidx & 127) * BROWS;

    // exp(s) = 2^(s*log2e); constant -4 folded into the MFMA C-init keeps
    // p' = e^(s-4) within e4m3 range.
    const float scale = 1.44269504088896340736f / (float)(*isf_p);
    const float SINIT = -4.0f * 1.44269504088896340736f;

    // Q B-frag: byte(lane: j) = fp8(Q[qbase + l31][u*32 + j] * scale)
    intx8 qf;
    {
        const float* qp = q + ((size_t)b * SQd + qbase + l31) * DDIM + u * 32;
        #pragma unroll
        for (int d = 0; d < 8; ++d) {
            const float4 a = *(const float4*)(qp + 4 * d);
            int w = pk2<false>(a.x * scale, a.y * scale, 0);
            w     = pk2<true >(a.z * scale, a.w * scale, w);
            qf[d] = w;
        }
    }

    const char* kg = kws + (size_t)(b * NTILES + g * TPG) * 2048 + lane * 32;
    const char* vg = vws + (size_t)(b * NCHUNK + g * CPG) * 4096 + lane * 32;
    const int cph  = bidx & (CPG - 1);   // decorrelate L2 streams across CUs

    floatx16 sinit16, o0, o1;
    #pragma unroll
    for (int i = 0; i < 16; ++i) { sinit16[i] = SINIT; o0[i] = 0.f; o1[i] = 0.f; }
    float l_acc = 0.f;

    #pragma unroll 1
    for (int c = 0; c < CPG; ++c) {
        const size_t off = (size_t)((c + cph) & (CPG - 1)) * 4096;
        // K tiles only (16 regs).
        const int4 ka0 = *(const int4*)(kg + off);
        const int4 ka1 = *(const int4*)(kg + off + 16);
        const int4 kb0 = *(const int4*)(kg + off + 2048);
        const int4 kb1 = *(const int4*)(kg + off + 2064);

        intx8 pa;
        // ---- tile A: QK issues, then V loads reuse the freed K-A regs ----
        floatx16 s = __builtin_amdgcn_mfma_scale_f32_32x32x64_f8f6f4(
            mk8(ka0, ka1), qf, sinit16, 0, 0, 0, 0x7F7F7F7F, 0, 0x7F7F7F7F);

        const int4 va0 = *(const int4*)(vg + off);
        const int4 va1 = *(const int4*)(vg + off + 16);
        const int4 vb0 = *(const int4*)(vg + off + 2048);
        const int4 vb1 = *(const int4*)(vg + off + 2064);

        {
            #pragma unroll
            for (int r = 0; r < 16; ++r) s[r] = __builtin_amdgcn_exp2f(s[r]);
            l_acc += ((((s[0] + s[1]) + (s[2] + s[3])) + ((s[4] + s[5]) + (s[6] + s[7])))
                   + (((s[8] + s[9]) + (s[10] + s[11])) + ((s[12] + s[13]) + (s[14] + s[15]))));
            #pragma unroll
            for (int d2 = 0; d2 < 4; ++d2) {
                int w = pk2<false>(s[4 * d2], s[4 * d2 + 1], 0);
                pa[d2] = pk2<true>(s[4 * d2 + 2], s[4 * d2 + 3], w);
            }
        }
        // ---- tile B (s regs reused) ----
        {
            floatx16 s2 = __builtin_amdgcn_mfma_scale_f32_32x32x64_f8f6f4(
                mk8(kb0, kb1), qf, sinit16, 0, 0, 0, 0x7F7F7F7F, 0, 0x7F7F7F7F);
            #pragma unroll
            for (int r = 0; r < 16; ++r) s2[r] = __builtin_amdgcn_exp2f(s2[r]);
            l_acc += ((((s2[0] + s2[1]) + (s2[2] + s2[3])) + ((s2[4] + s2[5]) + (s2[6] + s2[7])))
                   + (((s2[8] + s2[9]) + (s2[10] + s2[11])) + ((s2[12] + s2[13]) + (s2[14] + s2[15]))));
            #pragma unroll
            for (int d2 = 0; d2 < 4; ++d2) {
                int w = pk2<false>(s2[4 * d2], s2[4 * d2 + 1], 0);
                pa[4 + d2] = pk2<true>(s2[4 * d2 + 2], s2[4 * d2 + 3], w);
            }
        }
        // ---- PV ----
        o0 = __builtin_amdgcn_mfma_scale_f32_32x32x64_f8f6f4(
            pa, mk8(va0, va1), o0, 0, 0, 0, 0x7F7F7F7F, 0, 0x7F7F7F7F);
        o1 = __builtin_amdgcn_mfma_scale_f32_32x32x64_f8f6f4(
            pa, mk8(vb0, vb1), o1, 0, 0, 0, 0x7F7F7F7F, 0, 0x7F7F7F7F);
    }

    // Row denominators: lanes l and l+32 hold complementary key halves of
    // qrow = l31.
    l_acc += __shfl_xor(l_acc, 32);
    if (u == 0) C.Lred[l31][g] = l_acc;

    // Cross-group combine: groups 0-3 write slots, barrier, groups 4-7 add.
    // O layout: o_h[r] = O[qrow=(r&3)+8*(r>>2)+4u][d = h*32 + l31]
    if (g < 4) {
        #pragma unroll
        for (int r = 0; r < 16; ++r) {
            const int row = (r & 3) + 8 * (r >> 2) + 4 * u;
            C.Ored[row][g][l31]      = o0[r];
            C.Ored[row][g][32 + l31] = o1[r];
        }
    }
    __syncthreads();
    if (g >= 4) {
        #pragma unroll
        for (int r = 0; r < 16; ++r) {
            const int row = (r & 3) + 8 * (r >> 2) + 4 * u;
            C.Ored[row][g - 4][l31]      += o0[r];
            C.Ored[row][g - 4][32 + l31] += o1[r];
        }
    }
    __syncthreads();

    // Epilogue: out = attn@v + q; 3x { x += 2q; sigmoid; clamp }. Each thread
    // owns 4 consecutive d of one row (512 thr x 4 = 32 rows x 64 d).
    {
        const int row = tid >> 4;
        const int d4  = (tid & 15) * 4;
        float l = 0.0f;
        #pragma unroll
        for (int gg = 0; gg < NG; ++gg) l += C.Lred[row][gg];
        const float rl = 1.0f / l;
        float xs[4] = {0.f, 0.f, 0.f, 0.f};
        #pragma unroll
        for (int s = 0; s < 4; ++s) {
            const float4 t4 = *(const float4*)&C.Ored[row][s][d4];
            xs[0] += t4.x; xs[1] += t4.y; xs[2] += t4.z; xs[3] += t4.w;
        }
        const size_t idx = ((size_t)b * SQd + qbase + row) * DDIM + d4;
        const float4 q4v = *(const float4*)(q + idx);
        const float qs[4] = {q4v.x, q4v.y, q4v.z, q4v.w};
        #pragma unroll
        for (int c = 0; c < 4; ++c) {
            float x = xs[c] * rl + qs[c];
            #pragma unroll
            for (int itc = 0; itc < 3; ++itc) {
                x = x + 2.0f * qs[c];
                x = 1.0f / (1.0f + __expf(-x));
                x = fminf(fmaxf(x, 0.0f), 1.0f);
            }
            xs[c] = x;
        }
        const float4 r4 = {xs[0], xs[1], xs[2], xs[3]};
        *(float4*)(out + idx) = r4;
    }
}

extern "C" void kernel_launch(void* const* d_in, const int* in_sizes, int n_in,
                              void* d_out, int out_size, void* d_ws, size_t ws_size,
                              hipStream_t stream) {
    const float* q = (const float*)d_in[0];
    const float* k = (const float*)d_in[1];
    const float* v = (const float*)d_in[2];
    const int* isf = (const int*)d_in[3];
    float* out = (float*)d_out;
    char* ws = (char*)d_ws;   // Kws: 1 MB, Vws: 1 MB (fp8)

    prepack_kernel<<<dim3(4 * NTILES), dim3(256), 0, stream>>>(k, v, ws);

    const int nblocks = 4 * (SQd / BROWS);  // 512 blocks x 512 threads, 2/CU
    fattn_kernel<<<dim3(nblocks), dim3(512), 0, stream>>>(
        q, isf, ws, ws + KWS_BYTES, out);
}

// Round 4
// 89.116 us; speedup vs baseline: 1.3538x; 1.0033x over previous
//
#include <hip/hip_runtime.h>

#define SQd 4096
#define SKVd 4096
#define DDIM 64
#define BK 32                          // keys per tile
#define NG 8                           // key groups (waves) per block
#define NTILES (SKVd / BK)             // 128 tiles per batch
#define NCHUNK (NTILES / 2)            // 64 chunks (64 keys) per batch
#define TPG (NTILES / NG)              // 16 tiles per wave
#define CPG (TPG / 2)                  // 8 chunks per wave
#define KWS_BYTES ((size_t)4 * NTILES * 2048)   // 1 MB fp8 K
#define BROWS 32                       // q-rows per block (= per wave now)

typedef float floatx4  __attribute__((ext_vector_type(4)));
typedef float floatx16 __attribute__((ext_vector_type(16)));
typedef int   intx8    __attribute__((ext_vector_type(8)));

// Word-select must be an immediate constant -> template parameter.
template <bool HI>
__device__ inline int pk2(float a, float b, int old) {
    return __builtin_amdgcn_cvt_pk_fp8_f32(a, b, old, HI);
}

__device__ inline intx8 mk8(int4 a, int4 b) {
    intx8 r;
    r[0] = a.x; r[1] = a.y; r[2] = a.z; r[3] = a.w;
    r[4] = b.x; r[5] = b.y; r[6] = b.z; r[7] = b.w;
    return r;
}

// LDS: cross-group combine only (8 key-groups -> 4 slots, 2 rounds).
// 35840 B per block -> 2 blocks/CU co-resident.
struct CombS {
    float Ored[BROWS][4][68];
    float Lred[BROWS][NG];
};

// ---------------- Pre-pass: pack K and V for 32x32x64 f8f6f4 MFMA ----------
// K A-frag  (per 32-key tile, 2048 B): byte(lane*32 + j) =
//     fp8( K[tile*32 + (lane&31)][(lane>>5)*32 + j] ),  j = 0..31
// V B-frag  (per 64-key chunk, per d-half, 2048 B): byte(lane*32 + pt*16 + r) =
//     fp8( V[chunk*64 + pt*32 + (r&3)+8*(r>>2)+4*(lane>>5)][h*32 + (lane&31)] )
// The key permutation matches the 32x32 MFMA C-layout of QK^T, so exp'd P
// bytes feed the PV A-operand directly.
__global__ __launch_bounds__(256)
void prepack_kernel(const float* __restrict__ k, const float* __restrict__ v,
                    char* __restrict__ ws)
{
    __shared__ __align__(16) float Kt[BK][68];
    __shared__ __align__(16) float Vt[BK][68];

    const int blk  = blockIdx.x;          // b*NTILES + tile
    const int b    = blk >> 7;
    const int tile = blk & (NTILES - 1);
    const int tid  = threadIdx.x;

    const size_t base = ((size_t)b * SKVd + tile * BK) * DDIM;
    {
        const int row = tid >> 3, col = (tid & 7) * 8;
        const float4 k0 = *(const float4*)(k + base + (size_t)row * DDIM + col);
        const float4 k1 = *(const float4*)(k + base + (size_t)row * DDIM + col + 4);
        *(float4*)&Kt[row][col] = k0; *(float4*)&Kt[row][col + 4] = k1;
        const float4 v0 = *(const float4*)(v + base + (size_t)row * DDIM + col);
        const float4 v1 = *(const float4*)(v + base + (size_t)row * DDIM + col + 4);
        *(float4*)&Vt[row][col] = v0; *(float4*)&Vt[row][col + 4] = v1;
    }
    __syncthreads();

    const int lane = tid & 63;
    const int q4   = tid >> 6;            // 0..3: sub-slice of the lane's 32 B
    const int l31  = lane & 31;
    const int u    = lane >> 5;

    // K pack: 8 bytes per thread
    {
        const float* s = &Kt[l31][u * 32 + q4 * 8];
        int w0 = pk2<false>(s[0], s[1], 0); w0 = pk2<true>(s[2], s[3], w0);
        int w1 = pk2<false>(s[4], s[5], 0); w1 = pk2<true>(s[6], s[7], w1);
        int2 o2; o2.x = w0; o2.y = w1;
        *(int2*)(ws + (size_t)(b * NTILES + tile) * 2048 + lane * 32 + q4 * 8) = o2;
    }
    // V pack: 8 bytes per thread (h = d-half, rh = reg offset)
    {
        const int h  = q4 >> 1;
        const int rh = (q4 & 1) * 8;
        float p[8];
        #pragma unroll
        for (int i = 0; i < 8; ++i) {
            const int r   = rh + i;
            const int key = (r & 3) + 8 * (r >> 2) + 4 * u;
            p[i] = Vt[key][h * 32 + l31];
        }
        int w0 = pk2<false>(p[0], p[1], 0); w0 = pk2<true>(p[2], p[3], w0);
        int w1 = pk2<false>(p[4], p[5], 0); w1 = pk2<true>(p[6], p[7], w1);
        int2 o2; o2.x = w0; o2.y = w1;
        const size_t voff = KWS_BYTES
            + ((size_t)(b * NCHUNK + (tile >> 1)) * 2 + h) * 2048
            + lane * 32 + (tile & 1) * 16 + rh;
        *(int2*)(ws + voff) = o2;
    }
}

// ---------------- Main kernel ---------------------------------------------
// Wave = 32 q-rows x 512 keys (8 chunks of 64 keys).
// Loop-carried register prefetch: chunk c+1's K/V loads issue while chunk c
// computes, so every s_waitcnt targets loads issued a full chunk (~700 cyc)
// earlier -> zero exposed L2 latency. (R2/R3's same-iteration loads stalled
// ~250 cyc per chunk; the compiler hoists source-level staggering, but it
// cannot undo a loop-carried dependency.)
// Register diet: QK C-init is inline-const 0 (rematerializable); the -4*log2e
// shift is one v_add_f32 (SGPR operand) in the exp argument — bit-identical
// math, frees the 16 loop-live VGPRs sinit16 used to occupy. Peak live ~116.
__global__ __launch_bounds__(512, 4)
void fattn_kernel(const float* __restrict__ q, const int* __restrict__ isf_p,
                  const char* __restrict__ kws, const char* __restrict__ vws,
                  float* __restrict__ out)
{
    __shared__ CombS C;

    const int tid  = threadIdx.x;
    const int g    = tid >> 6;    // key group 0..7 (512 keys)
    const int lane = tid & 63;
    const int l31  = lane & 31;
    const int u    = lane >> 5;

    const int bidx  = blockIdx.x;       // 0..511
    const int b     = bidx >> 7;        // batch
    const int qbase = (bidx & 127) * BROWS;

    // exp(s) = 2^(s*log2e); constant -4 keeps p' = e^(s-4) within e4m3 range.
    const float scale = 1.44269504088896340736f / (float)(*isf_p);
    const float SINIT = -4.0f * 1.44269504088896340736f;

    // Q B-frag: byte(lane: j) = fp8(Q[qbase + l31][u*32 + j] * scale)
    intx8 qf;
    {
        const float* qp = q + ((size_t)b * SQd + qbase + l31) * DDIM + u * 32;
        #pragma unroll
        for (int d = 0; d < 8; ++d) {
            const float4 a = *(const float4*)(qp + 4 * d);
            int w = pk2<false>(a.x * scale, a.y * scale, 0);
            w     = pk2<true >(a.z * scale, a.w * scale, w);
            qf[d] = w;
        }
    }

    const char* kg = kws + (size_t)(b * NTILES + g * TPG) * 2048 + lane * 32;
    const char* vg = vws + (size_t)(b * NCHUNK + g * CPG) * 4096 + lane * 32;
    const int cph  = bidx & (CPG - 1);   // decorrelate L2 streams across CUs

    floatx16 o0, o1;
    #pragma unroll
    for (int i = 0; i < 16; ++i) { o0[i] = 0.f; o1[i] = 0.f; }
    const floatx16 zc = o0;              // zero C-init (inline-const remat)
    float l_acc = 0.f;

    // ---- prologue: chunk 0 in flight ----
    int4 k0, k1, k2, k3, v0, v1, v2, v3;
    {
        const size_t off = (size_t)(cph & (CPG - 1)) * 4096;
        k0 = *(const int4*)(kg + off);        k1 = *(const int4*)(kg + off + 16);
        k2 = *(const int4*)(kg + off + 2048); k3 = *(const int4*)(kg + off + 2064);
        v0 = *(const int4*)(vg + off);        v1 = *(const int4*)(vg + off + 16);
        v2 = *(const int4*)(vg + off + 2048); v3 = *(const int4*)(vg + off + 2064);
    }

    #pragma unroll 1
    for (int c = 0; c < CPG; ++c) {
        const size_t offn = (size_t)((c + 1 + cph) & (CPG - 1)) * 4096;

        intx8 pa;
        // ---- tile A: QK -> prefetch K(next) -> exp -> pack pa[0..3] ----
        floatx16 s = __builtin_amdgcn_mfma_scale_f32_32x32x64_f8f6f4(
            mk8(k0, k1), qf, zc, 0, 0, 0, 0x7F7F7F7F, 0, 0x7F7F7F7F);

        const int4 nk0 = *(const int4*)(kg + offn);
        const int4 nk1 = *(const int4*)(kg + offn + 16);
        const int4 nk2 = *(const int4*)(kg + offn + 2048);
        const int4 nk3 = *(const int4*)(kg + offn + 2064);

        #pragma unroll
        for (int r = 0; r < 16; ++r) s[r] = __builtin_amdgcn_exp2f(s[r] + SINIT);
        l_acc += ((((s[0] + s[1]) + (s[2] + s[3])) + ((s[4] + s[5]) + (s[6] + s[7])))
               + (((s[8] + s[9]) + (s[10] + s[11])) + ((s[12] + s[13]) + (s[14] + s[15]))));
        #pragma unroll
        for (int d2 = 0; d2 < 4; ++d2) {
            int w = pk2<false>(s[4 * d2], s[4 * d2 + 1], 0);
            pa[d2] = pk2<true>(s[4 * d2 + 2], s[4 * d2 + 3], w);
        }

        // ---- tile B: QK -> prefetch V(next) -> exp -> pack pa[4..7] ----
        floatx16 s2 = __builtin_amdgcn_mfma_scale_f32_32x32x64_f8f6f4(
            mk8(k2, k3), qf, zc, 0, 0, 0, 0x7F7F7F7F, 0, 0x7F7F7F7F);

        const int4 nv0 = *(const int4*)(vg + offn);
        const int4 nv1 = *(const int4*)(vg + offn + 16);
        const int4 nv2 = *(const int4*)(vg + offn + 2048);
        const int4 nv3 = *(const int4*)(vg + offn + 2064);

        #pragma unroll
        for (int r = 0; r < 16; ++r) s2[r] = __builtin_amdgcn_exp2f(s2[r] + SINIT);
        l_acc += ((((s2[0] + s2[1]) + (s2[2] + s2[3])) + ((s2[4] + s2[5]) + (s2[6] + s2[7])))
               + (((s2[8] + s2[9]) + (s2[10] + s2[11])) + ((s2[12] + s2[13]) + (s2[14] + s2[15]))));
        #pragma unroll
        for (int d2 = 0; d2 < 4; ++d2) {
            int w = pk2<false>(s2[4 * d2], s2[4 * d2 + 1], 0);
            pa[4 + d2] = pk2<true>(s2[4 * d2 + 2], s2[4 * d2 + 3], w);
        }

        // ---- PV on current V ----
        o0 = __builtin_amdgcn_mfma_scale_f32_32x32x64_f8f6f4(
            pa, mk8(v0, v1), o0, 0, 0, 0, 0x7F7F7F7F, 0, 0x7F7F7F7F);
        o1 = __builtin_amdgcn_mfma_scale_f32_32x32x64_f8f6f4(
            pa, mk8(v2, v3), o1, 0, 0, 0, 0x7F7F7F7F, 0, 0x7F7F7F7F);

        // rotate prefetched regs into current
        k0 = nk0; k1 = nk1; k2 = nk2; k3 = nk3;
        v0 = nv0; v1 = nv1; v2 = nv2; v3 = nv3;
    }

    // Row denominators: lanes l and l+32 hold complementary key halves of
    // qrow = l31.
    l_acc += __shfl_xor(l_acc, 32);
    if (u == 0) C.Lred[l31][g] = l_acc;

    // Cross-group combine: groups 0-3 write slots, barrier, groups 4-7 add.
    // O layout: o_h[r] = O[qrow=(r&3)+8*(r>>2)+4u][d = h*32 + l31]
    if (g < 4) {
        #pragma unroll
        for (int r = 0; r < 16; ++r) {
            const int row = (r & 3) + 8 * (r >> 2) + 4 * u;
            C.Ored[row][g][l31]      = o0[r];
            C.Ored[row][g][32 + l31] = o1[r];
        }
    }
    __syncthreads();
    if (g >= 4) {
        #pragma unroll
        for (int r = 0; r < 16; ++r) {
            const int row = (r & 3) + 8 * (r >> 2) + 4 * u;
            C.Ored[row][g - 4][l31]      += o0[r];
            C.Ored[row][g - 4][32 + l31] += o1[r];
        }
    }
    __syncthreads();

    // Epilogue: out = attn@v + q; 3x { x += 2q; sigmoid; clamp }. Each thread
    // owns 4 consecutive d of one row (512 thr x 4 = 32 rows x 64 d).
    {
        const int row = tid >> 4;
        const int d4  = (tid & 15) * 4;
        float l = 0.0f;
        #pragma unroll
        for (int gg = 0; gg < NG; ++gg) l += C.Lred[row][gg];
        const float rl = 1.0f / l;
        float xs[4] = {0.f, 0.f, 0.f, 0.f};
        #pragma unroll
        for (int s = 0; s < 4; ++s) {
            const float4 t4 = *(const float4*)&C.Ored[row][s][d4];
            xs[0] += t4.x; xs[1] += t4.y; xs[2] += t4.z; xs[3] += t4.w;
        }
        const size_t idx = ((size_t)b * SQd + qbase + row) * DDIM + d4;
        const float4 q4v = *(const float4*)(q + idx);
        const float qs[4] = {q4v.x, q4v.y, q4v.z, q4v.w};
        #pragma unroll
        for (int c = 0; c < 4; ++c) {
            float x = xs[c] * rl + qs[c];
            #pragma unroll
            for (int itc = 0; itc < 3; ++itc) {
                x = x + 2.0f * qs[c];
                x = 1.0f / (1.0f + __expf(-x));
                x = fminf(fmaxf(x, 0.0f), 1.0f);
            }
            xs[c] = x;
        }
        const float4 r4 = {xs[0], xs[1], xs[2], xs[3]};
        *(float4*)(out + idx) = r4;
    }
}

extern "C" void kernel_launch(void* const* d_in, const int* in_sizes, int n_in,
                              void* d_out, int out_size, void* d_ws, size_t ws_size,
                              hipStream_t stream) {
    const float* q = (const float*)d_in[0];
    const float* k = (const float*)d_in[1];
    const float* v = (const float*)d_in[2];
    const int* isf = (const int*)d_in[3];
    float* out = (float*)d_out;
    char* ws = (char*)d_ws;   // Kws: 1 MB, Vws: 1 MB (fp8)

    prepack_kernel<<<dim3(4 * NTILES), dim3(256), 0, stream>>>(k, v, ws);

    const int nblocks = 4 * (SQd / BROWS);  // 512 blocks x 512 threads, 2/CU
    fattn_kernel<<<dim3(nblocks), dim3(512), 0, stream>>>(
        q, isf, ws, ws + KWS_BYTES, out);
}